// Round 9
// baseline (122.965 us; speedup 1.0000x reference)
//
#include <hip/hip_runtime.h>
#include <math.h>

#ifndef M_PI
#define M_PI 3.14159265358979323846
#endif

constexpr int N    = 1024;
constexpr int M    = 4096;
constexpr int RANK = 32;
constexpr float PHI1 = -1.5339807878856412e-3f;   // -2*pi/4096

__device__ __forceinline__ float softplus_f(float x) {
    return (x > 0.0f) ? (x + log1pf(__expf(-x))) : log1pf(__expf(x));
}

// ===========================================================================
// Fused Cooley-Tukey 64x64 DFT of softplus(H): writes PLANAR HfR / HfI.
// grid (4 mGroups x 32 d), block 256.  ~10 us (validated rounds 5-7).
// ===========================================================================
__global__ __launch_bounds__(256) void dft_fused(const float* __restrict__ H,
                                                 float* __restrict__ HfR,
                                                 float* __restrict__ HfI) {
    __shared__ float  sh[M];             // 16 KB
    __shared__ float2 sG[64 * 65];       // 33.3 KB, pad 65
    const int d = blockIdx.y, tid = threadIdx.x;
    for (int k = tid; k < M; k += 256) sh[k] = softplus_f(H[d * M + k]);
    __syncthreads();

    const int k0 = tid & 63;
    const int rB = (tid >> 6) * 16;
    float twR[16], twI[16], stR[16], stI[16], aR[16], aI[16];
    #pragma unroll
    for (int rr = 0; rr < 16; ++rr) {
        const float ang = (-2.0f * (float)M_PI / 64.0f) * (float)(rB + rr);
        __sincosf(ang, &stI[rr], &stR[rr]);
        twR[rr] = 1.f; twI[rr] = 0.f; aR[rr] = 0.f; aI[rr] = 0.f;
    }
    for (int k1 = 0; k1 < 64; ++k1) {
        const float h = sh[(k1 << 6) + k0];
        #pragma unroll
        for (int rr = 0; rr < 16; ++rr) {
            aR[rr] = fmaf(h, twR[rr], aR[rr]);
            aI[rr] = fmaf(h, twI[rr], aI[rr]);
            const float nR = fmaf(twR[rr], stR[rr], -twI[rr] * stI[rr]);
            const float nI = fmaf(twR[rr], stI[rr],  twI[rr] * stR[rr]);
            twR[rr] = nR; twI[rr] = nI;
        }
    }
    #pragma unroll
    for (int rr = 0; rr < 16; ++rr)
        sG[k0 * 65 + rB + rr] = make_float2(aR[rr], aI[rr]);
    __syncthreads();

    const int mBase = blockIdx.x * 1024;
    for (int j = 0; j < 4; ++j) {
        const int m = mBase + j * 256 + tid;
        const int r = m & 63;
        float ss, sc; __sincosf(PHI1 * (float)m, &ss, &sc);
        float tR_ = 1.f, tI_ = 0.f, accR = 0.f, accI = 0.f;
        #pragma unroll 8
        for (int q = 0; q < 64; ++q) {
            const float2 g = sG[q * 65 + r];
            accR = fmaf(tR_, g.x, fmaf(-tI_, g.y, accR));
            accI = fmaf(tR_, g.y, fmaf( tI_, g.x, accI));
            const float nR = fmaf(tR_, sc, -tI_ * ss);
            const float nI = fmaf(tR_, ss,  tI_ * sc);
            tR_ = nR; tI_ = nI;
        }
        HfR[d * M + m] = accR;
        HfI[d * M + m] = accI;
    }
}

// ===========================================================================
// Einsum v5b: V[n,m] = sum_d spW[n,d] e^{-2pi i tau[n,d] m/M} Hf[d,m]
// m-tile 128, U=2 rows/thread, 32 rows/block -> grid (32,32) = 1024 blocks
// (4 blocks/CU, 16 waves/CU; LDS 24 KB).
// R8 BUG FIX: staging must cover 16*(MT/2)=1024 float4 (64 float4 per d-row):
//   dl = e4 >> 6, p = e4 & 63, mm = 2p in [0,128).  (R8 staged half the tile
//   at the wrong row stride -> absmax 72k.)
// ===========================================================================
template <bool CPLX>
__global__ __launch_bounds__(256) void einsum_kernel(const float* __restrict__ W,
                                                     const float* __restrict__ tau,
                                                     const float* __restrict__ HfR,
                                                     const float* __restrict__ HfI,
                                                     float* __restrict__ out_f) {
    constexpr int U     = 2;
    constexpr int ROWS  = 32;                      // 16 nl-groups x U
    constexpr int MT    = 128;                     // m-tile
    __shared__ float2 sHf[16 * MT];                // 16 KB (one 16-d half)
    __shared__ float  sW[ROWS][RANK], sT[ROWS][RANK];  // 8 KB
    const int tid   = threadIdx.x;
    const int mBase = blockIdx.x * MT;
    const int nBase = blockIdx.y * ROWS;

    for (int i = tid; i < ROWS * RANK; i += 256) {
        const int n_ = i >> 5, dd = i & 31;
        sW[n_][dd] = softplus_f(W[(nBase + n_) * RANK + dd]);
        sT[n_][dd] = tau[(nBase + n_) * RANK + dd];
    }

    const int nl = tid >> 4, chunk = tid & 15;
    const int m0 = mBase + chunk;

    float accR[U][8], accI[U][8];
    #pragma unroll
    for (int u = 0; u < U; ++u)
        #pragma unroll
        for (int j = 0; j < 8; ++j) { accR[u][j] = 0.f; if (CPLX) accI[u][j] = 0.f; }

    for (int half = 0; half < 2; ++half) {
        __syncthreads();   // protect prior readers; covers sW/sT at half 0
        for (int e4 = tid; e4 < 16 * (MT / 2); e4 += 256) {   // 1024 float4, 4 iters
            const int dl = e4 >> 6, p = e4 & 63;              // 64 float4 per d-row
            const int base = (half * 16 + dl) * M + mBase + (p << 1);
            const float2 r2 = *(const float2*)(HfR + base);
            const float2 q2 = *(const float2*)(HfI + base);
            ((float4*)sHf)[e4] = make_float4(r2.x, q2.x, r2.y, q2.y);
        }
        __syncthreads();

        #pragma unroll 1
        for (int dl = 0; dl < 16; ++dl) {
            const int dd = (half << 4) + dl;
            float tR_[U], tI_[U], sc[U], ss[U];
            #pragma unroll
            for (int u = 0; u < U; ++u) {
                const float t = sT[nl * U + u][dd], w = sW[nl * U + u][dd];
                const float a1 = PHI1 * t;
                __sincosf(a1 * 16.0f, &ss[u], &sc[u]);        // stride-16 step
                float s0, c0; __sincosf(a1 * (float)m0, &s0, &c0);
                tR_[u] = w * c0; tI_[u] = w * s0;             // spW folded in
            }
            int idx = (dl << 7) + chunk;                      // row stride 128 float2
            #pragma unroll
            for (int j = 0; j < 8; ++j) {
                const float2 h = sHf[idx];
                #pragma unroll
                for (int u = 0; u < U; ++u) {
                    accR[u][j] = fmaf(tR_[u], h.x, fmaf(-tI_[u], h.y, accR[u][j]));
                    if (CPLX) accI[u][j] = fmaf(tR_[u], h.y, fmaf(tI_[u], h.x, accI[u][j]));
                    const float nR = fmaf(tR_[u], sc[u], -tI_[u] * ss[u]);
                    const float nI = fmaf(tR_[u], ss[u],  tI_[u] * sc[u]);
                    tR_[u] = nR; tI_[u] = nI;
                }
                idx += 16;
            }
        }
    }

    #pragma unroll
    for (int u = 0; u < U; ++u) {
        const int n = nBase + nl * U + u;
        if (CPLX) {
            float2* o2 = (float2*)out_f;
            #pragma unroll
            for (int j = 0; j < 8; ++j)
                o2[(size_t)n * M + m0 + (j << 4)] = make_float2(accR[u][j], accI[u][j]);
        } else {
            #pragma unroll
            for (int j = 0; j < 8; ++j)
                out_f[(size_t)n * M + m0 + (j << 4)] = accR[u][j];
        }
    }
}

// ===========================================================================
// Tail kernels (no-ws fallback only — dead given 268 MB ws, kept for safety).
// ===========================================================================
__global__ __launch_bounds__(256) void tail_real(const float* __restrict__ W,
                                                 const float* __restrict__ tau,
                                                 const float* __restrict__ stashR,
                                                 const float* __restrict__ stashI,
                                                 float* __restrict__ out_f) {
    __shared__ float stR[32 * 32], stI[32 * 32];
    __shared__ float sW[64][RANK], sT[64][RANK];
    const int tid = threadIdx.x;
    const int c0  = blockIdx.x * 32;
    const int nBase = N - 64;
    for (int i = tid; i < 64 * RANK; i += 256) {
        const int n_ = i >> 5, dd = i & 31;
        sW[n_][dd] = softplus_f(W[(nBase + n_) * RANK + dd]);
        sT[n_][dd] = tau[(nBase + n_) * RANK + dd];
    }
    for (int i = tid; i < 32 * 32; i += 256) {
        const int d_ = i >> 5, mm = i & 31;
        stR[i] = stashR[d_ * M + c0 + mm];
        stI[i] = stashI[d_ * M + c0 + mm];
    }
    __syncthreads();
    const int n = tid >> 2, chunk = tid & 3;
    const int m0 = c0 + chunk;
    float acc[8];
    #pragma unroll
    for (int j = 0; j < 8; ++j) acc[j] = 0.f;
    for (int d = 0; d < RANK; ++d) {
        const float t = sT[n][d], w = sW[n][d];
        const float a1 = PHI1 * t;
        float ss, sc; __sincosf(a1 * 4.0f, &ss, &sc);
        float s0, c0f; __sincosf(a1 * (float)m0, &s0, &c0f);
        float tR_ = w * c0f, tI_ = w * s0;
        int idx = (d << 5) + chunk;
        #pragma unroll
        for (int j = 0; j < 8; ++j) {
            acc[j] = fmaf(tR_, stR[idx], fmaf(-tI_, stI[idx], acc[j]));
            const float nR = fmaf(tR_, sc, -tI_ * ss);
            const float nI = fmaf(tR_, ss,  tI_ * sc);
            tR_ = nR; tI_ = nI;
            idx += 4;
        }
    }
    #pragma unroll
    for (int j = 0; j < 8; ++j)
        out_f[(size_t)(nBase + n) * M + m0 + (j << 2)] = acc[j];
}

__global__ __launch_bounds__(256) void tail_cplx(const float* __restrict__ W,
                                                 const float* __restrict__ tau,
                                                 const float* __restrict__ stashR,
                                                 const float* __restrict__ stashI,
                                                 float* __restrict__ out_f) {
    const int nBase = N - 32;
    __shared__ float sW[32][RANK], sT[32][RANK];
    const int tid = threadIdx.x, mBase = blockIdx.x * 256;
    for (int i = tid; i < 32 * RANK; i += 256) {
        const int n_ = i >> 5, dd = i & 31;
        sW[n_][dd] = softplus_f(W[(nBase + n_) * RANK + dd]);
        sT[n_][dd] = tau[(nBase + n_) * RANK + dd];
    }
    const int m = mBase + tid;
    float hr[RANK], hi[RANK];
    #pragma unroll
    for (int d = 0; d < RANK; ++d) { hr[d] = stashR[d * M + m]; hi[d] = stashI[d * M + m]; }
    __syncthreads();
    const float phi = PHI1 * (float)m;
    for (int n_ = 0; n_ < 32; ++n_) {
        float aR = 0.f, aI = 0.f;
        #pragma unroll
        for (int d = 0; d < RANK; ++d) {
            const float t = sT[n_][d], w = sW[n_][d];
            float s, c; __sincosf(t * phi, &s, &c);
            const float cw = c * w, sw = s * w;
            aR = fmaf(cw, hr[d], fmaf(-sw, hi[d], aR));
            aI = fmaf(cw, hi[d], fmaf( sw, hr[d], aI));
        }
        ((float2*)out_f)[(size_t)(nBase + n_) * M + m] = make_float2(aR, aI);
    }
}

// ---------------------------------------------------------------------------
extern "C" void kernel_launch(void* const* d_in, const int* in_sizes, int n_in,
                              void* d_out, int out_size, void* d_ws, size_t ws_size,
                              hipStream_t stream) {
    const float* W   = (const float*)d_in[0];
    const float* H   = (const float*)d_in[1];
    const float* tau = (const float*)d_in[2];
    float* out_f = (float*)d_out;

    const bool   cplx   = (out_size >= 2 * N * M);
    const size_t planeN = (size_t)RANK * M;            // 131072 floats / plane

    if (d_ws != nullptr && ws_size >= 2 * planeN * sizeof(float)) {
        float* HfR = (float*)d_ws;
        float* HfI = HfR + planeN;
        dft_fused<<<dim3(4, 32), 256, 0, stream>>>(H, HfR, HfI);
        if (cplx) einsum_kernel<true ><<<dim3(32, N / 32), 256, 0, stream>>>(W, tau, HfR, HfI, out_f);
        else      einsum_kernel<false><<<dim3(32, N / 32), 256, 0, stream>>>(W, tau, HfR, HfI, out_f);
    } else if (!cplx) {
        float* HfR = out_f + (size_t)(N - 64) * M;     // stash in last 64 real rows
        float* HfI = HfR + planeN;
        dft_fused<<<dim3(4, 32), 256, 0, stream>>>(H, HfR, HfI);
        einsum_kernel<false><<<dim3(32, (N - 64) / 32), 256, 0, stream>>>(W, tau, HfR, HfI, out_f);
        tail_real<<<dim3(128), 256, 0, stream>>>(W, tau, HfR, HfI, out_f);
    } else {
        float* HfR = out_f + 2 * (size_t)N * M - 2 * planeN;  // last 32 cplx rows
        float* HfI = HfR + planeN;
        dft_fused<<<dim3(4, 32), 256, 0, stream>>>(H, HfR, HfI);
        einsum_kernel<true ><<<dim3(32, (N - 32) / 32), 256, 0, stream>>>(W, tau, HfR, HfI, out_f);
        tail_cplx<<<dim3(16), 256, 0, stream>>>(W, tau, HfR, HfI, out_f);
    }
}

// Round 10
// 110.018 us; speedup vs baseline: 1.1177x; 1.1177x over previous
//
#include <hip/hip_runtime.h>
#include <math.h>

#ifndef M_PI
#define M_PI 3.14159265358979323846
#endif

constexpr int N    = 1024;
constexpr int M    = 4096;
constexpr int RANK = 32;
constexpr float PHI1 = -1.5339807878856412e-3f;   // -2*pi/4096

__device__ __forceinline__ float softplus_f(float x) {
    return (x > 0.0f) ? (x + log1pf(__expf(-x))) : log1pf(__expf(x));
}

// ===========================================================================
// DFT stage 1: G[d][r][k0] = sum_k1 sp(h[d][64k1+k0]) e^{-2pi i k1 r/64}
// grid (8 rG, 32 d), block 256. Thread: k0 = tid&63, two r-chains (12 regs,
// no spill). sh reads stride-1; G writes coalesced in k0.
// ===========================================================================
__global__ __launch_bounds__(256) void dft_s1(const float* __restrict__ H,
                                              float* __restrict__ GR,
                                              float* __restrict__ GI) {
    __shared__ float sh[M];              // 16 KB
    const int d = blockIdx.y, tid = threadIdx.x;
    const float4* H4 = (const float4*)(H + d * M);
    for (int i = tid; i < M / 4; i += 256) {
        const float4 v = H4[i];
        ((float4*)sh)[i] = make_float4(softplus_f(v.x), softplus_f(v.y),
                                       softplus_f(v.z), softplus_f(v.w));
    }
    __syncthreads();

    const int k0 = tid & 63;
    const int r0 = blockIdx.x * 8 + (tid >> 6) * 2;   // this thread: r0, r0+1
    float twR0 = 1.f, twI0 = 0.f, aR0 = 0.f, aI0 = 0.f;
    float twR1 = 1.f, twI1 = 0.f, aR1 = 0.f, aI1 = 0.f;
    float s0, c0, s1, c1;
    __sincosf((-2.0f * (float)M_PI / 64.0f) * (float)r0,       &s0, &c0);
    __sincosf((-2.0f * (float)M_PI / 64.0f) * (float)(r0 + 1), &s1, &c1);

    for (int k1 = 0; k1 < 64; ++k1) {
        const float h = sh[(k1 << 6) + k0];
        aR0 = fmaf(h, twR0, aR0);  aI0 = fmaf(h, twI0, aI0);
        aR1 = fmaf(h, twR1, aR1);  aI1 = fmaf(h, twI1, aI1);
        float nR = fmaf(twR0, c0, -twI0 * s0);
        float nI = fmaf(twR0, s0,  twI0 * c0);
        twR0 = nR; twI0 = nI;
        nR = fmaf(twR1, c1, -twI1 * s1);
        nI = fmaf(twR1, s1,  twI1 * c1);
        twR1 = nR; twI1 = nI;
    }
    const int base = d * 4096 + r0 * 64 + k0;
    GR[base]      = aR0;  GI[base]      = aI0;
    GR[base + 64] = aR1;  GI[base + 64] = aI1;
}

// ===========================================================================
// DFT stage 2: Hf[d][m] = sum_k0 G[d][m&63][k0] e^{-2pi i k0 m/4096}
// grid (16 mG, 32 d), block 256, one m per thread. G[d] staged to LDS with
// x65 padding: read addr 65r + k0 -> bank (r+k0)%32, 2-way max (free).
// ===========================================================================
__global__ __launch_bounds__(256) void dft_s2(const float* __restrict__ GR,
                                              const float* __restrict__ GI,
                                              float* __restrict__ HfR,
                                              float* __restrict__ HfI) {
    __shared__ float sGR[64 * 65], sGI[64 * 65];   // 33.3 KB
    const int d = blockIdx.y, tid = threadIdx.x;
    const float4* gr4 = (const float4*)(GR + d * 4096);
    const float4* gi4 = (const float4*)(GI + d * 4096);
    for (int i4 = tid; i4 < 1024; i4 += 256) {
        const int r = i4 >> 4, k0 = (i4 & 15) << 2;   // element = r*64 + k0
        const float4 vr = gr4[i4];
        const float4 vi = gi4[i4];
        const int p = r * 65 + k0;
        sGR[p] = vr.x; sGR[p+1] = vr.y; sGR[p+2] = vr.z; sGR[p+3] = vr.w;
        sGI[p] = vi.x; sGI[p+1] = vi.y; sGI[p+2] = vi.z; sGI[p+3] = vi.w;
    }
    __syncthreads();

    const int m = blockIdx.x * 256 + tid;
    const int rb = (m & 63) * 65;
    float ss, sc; __sincosf(PHI1 * (float)m, &ss, &sc);   // e^{-2pi i m/4096}
    float tR_ = 1.f, tI_ = 0.f, accR = 0.f, accI = 0.f;
    #pragma unroll 8
    for (int k0 = 0; k0 < 64; ++k0) {
        const float gr = sGR[rb + k0], gi = sGI[rb + k0];
        accR = fmaf(tR_, gr, fmaf(-tI_, gi, accR));
        accI = fmaf(tR_, gi, fmaf( tI_, gr, accI));
        const float nR = fmaf(tR_, sc, -tI_ * ss);
        const float nI = fmaf(tR_, ss,  tI_ * sc);
        tR_ = nR; tI_ = nI;
    }
    HfR[d * M + m] = accR;
    HfI[d * M + m] = accI;
}

// ===========================================================================
// dft_fused (no-ws fallback only — validated R5-R9, kept byte-identical).
// ===========================================================================
__global__ __launch_bounds__(256) void dft_fused(const float* __restrict__ H,
                                                 float* __restrict__ HfR,
                                                 float* __restrict__ HfI) {
    __shared__ float  sh[M];
    __shared__ float2 sG[64 * 65];
    const int d = blockIdx.y, tid = threadIdx.x;
    for (int k = tid; k < M; k += 256) sh[k] = softplus_f(H[d * M + k]);
    __syncthreads();

    const int k0 = tid & 63;
    const int rB = (tid >> 6) * 16;
    float twR[16], twI[16], stR[16], stI[16], aR[16], aI[16];
    #pragma unroll
    for (int rr = 0; rr < 16; ++rr) {
        const float ang = (-2.0f * (float)M_PI / 64.0f) * (float)(rB + rr);
        __sincosf(ang, &stI[rr], &stR[rr]);
        twR[rr] = 1.f; twI[rr] = 0.f; aR[rr] = 0.f; aI[rr] = 0.f;
    }
    for (int k1 = 0; k1 < 64; ++k1) {
        const float h = sh[(k1 << 6) + k0];
        #pragma unroll
        for (int rr = 0; rr < 16; ++rr) {
            aR[rr] = fmaf(h, twR[rr], aR[rr]);
            aI[rr] = fmaf(h, twI[rr], aI[rr]);
            const float nR = fmaf(twR[rr], stR[rr], -twI[rr] * stI[rr]);
            const float nI = fmaf(twR[rr], stI[rr],  twI[rr] * stR[rr]);
            twR[rr] = nR; twI[rr] = nI;
        }
    }
    #pragma unroll
    for (int rr = 0; rr < 16; ++rr)
        sG[k0 * 65 + rB + rr] = make_float2(aR[rr], aI[rr]);
    __syncthreads();

    const int mBase = blockIdx.x * 1024;
    for (int j = 0; j < 4; ++j) {
        const int m = mBase + j * 256 + tid;
        const int r = m & 63;
        float ss, sc; __sincosf(PHI1 * (float)m, &ss, &sc);
        float tR_ = 1.f, tI_ = 0.f, accR = 0.f, accI = 0.f;
        #pragma unroll 8
        for (int q = 0; q < 64; ++q) {
            const float2 g = sG[q * 65 + r];
            accR = fmaf(tR_, g.x, fmaf(-tI_, g.y, accR));
            accI = fmaf(tR_, g.y, fmaf( tI_, g.x, accI));
            const float nR = fmaf(tR_, sc, -tI_ * ss);
            const float nI = fmaf(tR_, ss,  tI_ * sc);
            tR_ = nR; tI_ = nI;
        }
        HfR[d * M + m] = accR;
        HfI[d * M + m] = accI;
    }
}

// ===========================================================================
// Einsum v5b — byte-identical to R9 (validated, absmax 1.0, ~41 us).
// ===========================================================================
template <bool CPLX>
__global__ __launch_bounds__(256) void einsum_kernel(const float* __restrict__ W,
                                                     const float* __restrict__ tau,
                                                     const float* __restrict__ HfR,
                                                     const float* __restrict__ HfI,
                                                     float* __restrict__ out_f) {
    constexpr int U     = 2;
    constexpr int ROWS  = 32;
    constexpr int MT    = 128;
    __shared__ float2 sHf[16 * MT];
    __shared__ float  sW[ROWS][RANK], sT[ROWS][RANK];
    const int tid   = threadIdx.x;
    const int mBase = blockIdx.x * MT;
    const int nBase = blockIdx.y * ROWS;

    for (int i = tid; i < ROWS * RANK; i += 256) {
        const int n_ = i >> 5, dd = i & 31;
        sW[n_][dd] = softplus_f(W[(nBase + n_) * RANK + dd]);
        sT[n_][dd] = tau[(nBase + n_) * RANK + dd];
    }

    const int nl = tid >> 4, chunk = tid & 15;
    const int m0 = mBase + chunk;

    float accR[U][8], accI[U][8];
    #pragma unroll
    for (int u = 0; u < U; ++u)
        #pragma unroll
        for (int j = 0; j < 8; ++j) { accR[u][j] = 0.f; if (CPLX) accI[u][j] = 0.f; }

    for (int half = 0; half < 2; ++half) {
        __syncthreads();
        for (int e4 = tid; e4 < 16 * (MT / 2); e4 += 256) {
            const int dl = e4 >> 6, p = e4 & 63;
            const int base = (half * 16 + dl) * M + mBase + (p << 1);
            const float2 r2 = *(const float2*)(HfR + base);
            const float2 q2 = *(const float2*)(HfI + base);
            ((float4*)sHf)[e4] = make_float4(r2.x, q2.x, r2.y, q2.y);
        }
        __syncthreads();

        #pragma unroll 1
        for (int dl = 0; dl < 16; ++dl) {
            const int dd = (half << 4) + dl;
            float tR_[U], tI_[U], sc[U], ss[U];
            #pragma unroll
            for (int u = 0; u < U; ++u) {
                const float t = sT[nl * U + u][dd], w = sW[nl * U + u][dd];
                const float a1 = PHI1 * t;
                __sincosf(a1 * 16.0f, &ss[u], &sc[u]);
                float s0, c0; __sincosf(a1 * (float)m0, &s0, &c0);
                tR_[u] = w * c0; tI_[u] = w * s0;
            }
            int idx = (dl << 7) + chunk;
            #pragma unroll
            for (int j = 0; j < 8; ++j) {
                const float2 h = sHf[idx];
                #pragma unroll
                for (int u = 0; u < U; ++u) {
                    accR[u][j] = fmaf(tR_[u], h.x, fmaf(-tI_[u], h.y, accR[u][j]));
                    if (CPLX) accI[u][j] = fmaf(tR_[u], h.y, fmaf(tI_[u], h.x, accI[u][j]));
                    const float nR = fmaf(tR_[u], sc[u], -tI_[u] * ss[u]);
                    const float nI = fmaf(tR_[u], ss[u],  tI_[u] * sc[u]);
                    tR_[u] = nR; tI_[u] = nI;
                }
                idx += 16;
            }
        }
    }

    #pragma unroll
    for (int u = 0; u < U; ++u) {
        const int n = nBase + nl * U + u;
        if (CPLX) {
            float2* o2 = (float2*)out_f;
            #pragma unroll
            for (int j = 0; j < 8; ++j)
                o2[(size_t)n * M + m0 + (j << 4)] = make_float2(accR[u][j], accI[u][j]);
        } else {
            #pragma unroll
            for (int j = 0; j < 8; ++j)
                out_f[(size_t)n * M + m0 + (j << 4)] = accR[u][j];
        }
    }
}

// ===========================================================================
// Tail kernels (no-ws fallback only — dead given 268 MB ws).
// ===========================================================================
__global__ __launch_bounds__(256) void tail_real(const float* __restrict__ W,
                                                 const float* __restrict__ tau,
                                                 const float* __restrict__ stashR,
                                                 const float* __restrict__ stashI,
                                                 float* __restrict__ out_f) {
    __shared__ float stR[32 * 32], stI[32 * 32];
    __shared__ float sW[64][RANK], sT[64][RANK];
    const int tid = threadIdx.x;
    const int c0  = blockIdx.x * 32;
    const int nBase = N - 64;
    for (int i = tid; i < 64 * RANK; i += 256) {
        const int n_ = i >> 5, dd = i & 31;
        sW[n_][dd] = softplus_f(W[(nBase + n_) * RANK + dd]);
        sT[n_][dd] = tau[(nBase + n_) * RANK + dd];
    }
    for (int i = tid; i < 32 * 32; i += 256) {
        const int d_ = i >> 5, mm = i & 31;
        stR[i] = stashR[d_ * M + c0 + mm];
        stI[i] = stashI[d_ * M + c0 + mm];
    }
    __syncthreads();
    const int n = tid >> 2, chunk = tid & 3;
    const int m0 = c0 + chunk;
    float acc[8];
    #pragma unroll
    for (int j = 0; j < 8; ++j) acc[j] = 0.f;
    for (int d = 0; d < RANK; ++d) {
        const float t = sT[n][d], w = sW[n][d];
        const float a1 = PHI1 * t;
        float ss, sc; __sincosf(a1 * 4.0f, &ss, &sc);
        float s0, c0f; __sincosf(a1 * (float)m0, &s0, &c0f);
        float tR_ = w * c0f, tI_ = w * s0;
        int idx = (d << 5) + chunk;
        #pragma unroll
        for (int j = 0; j < 8; ++j) {
            acc[j] = fmaf(tR_, stR[idx], fmaf(-tI_, stI[idx], acc[j]));
            const float nR = fmaf(tR_, sc, -tI_ * ss);
            const float nI = fmaf(tR_, ss,  tI_ * sc);
            tR_ = nR; tI_ = nI;
            idx += 4;
        }
    }
    #pragma unroll
    for (int j = 0; j < 8; ++j)
        out_f[(size_t)(nBase + n) * M + m0 + (j << 2)] = acc[j];
}

__global__ __launch_bounds__(256) void tail_cplx(const float* __restrict__ W,
                                                 const float* __restrict__ tau,
                                                 const float* __restrict__ stashR,
                                                 const float* __restrict__ stashI,
                                                 float* __restrict__ out_f) {
    const int nBase = N - 32;
    __shared__ float sW[32][RANK], sT[32][RANK];
    const int tid = threadIdx.x, mBase = blockIdx.x * 256;
    for (int i = tid; i < 32 * RANK; i += 256) {
        const int n_ = i >> 5, dd = i & 31;
        sW[n_][dd] = softplus_f(W[(nBase + n_) * RANK + dd]);
        sT[n_][dd] = tau[(nBase + n_) * RANK + dd];
    }
    const int m = mBase + tid;
    float hr[RANK], hi[RANK];
    #pragma unroll
    for (int d = 0; d < RANK; ++d) { hr[d] = stashR[d * M + m]; hi[d] = stashI[d * M + m]; }
    __syncthreads();
    const float phi = PHI1 * (float)m;
    for (int n_ = 0; n_ < 32; ++n_) {
        float aR = 0.f, aI = 0.f;
        #pragma unroll
        for (int d = 0; d < RANK; ++d) {
            const float t = sT[n_][d], w = sW[n_][d];
            float s, c; __sincosf(t * phi, &s, &c);
            const float cw = c * w, sw = s * w;
            aR = fmaf(cw, hr[d], fmaf(-sw, hi[d], aR));
            aI = fmaf(cw, hi[d], fmaf( sw, hr[d], aI));
        }
        ((float2*)out_f)[(size_t)(nBase + n_) * M + m] = make_float2(aR, aI);
    }
}

// ---------------------------------------------------------------------------
extern "C" void kernel_launch(void* const* d_in, const int* in_sizes, int n_in,
                              void* d_out, int out_size, void* d_ws, size_t ws_size,
                              hipStream_t stream) {
    const float* W   = (const float*)d_in[0];
    const float* H   = (const float*)d_in[1];
    const float* tau = (const float*)d_in[2];
    float* out_f = (float*)d_out;

    const bool   cplx   = (out_size >= 2 * N * M);
    const size_t planeN = (size_t)RANK * M;            // 131072 floats / plane

    if (d_ws != nullptr && ws_size >= 4 * planeN * sizeof(float)) {
        float* HfR = (float*)d_ws;
        float* HfI = HfR + planeN;
        float* GR  = HfI + planeN;
        float* GI  = GR  + planeN;
        dft_s1<<<dim3(8, 32), 256, 0, stream>>>(H, GR, GI);
        dft_s2<<<dim3(16, 32), 256, 0, stream>>>(GR, GI, HfR, HfI);
        if (cplx) einsum_kernel<true ><<<dim3(32, N / 32), 256, 0, stream>>>(W, tau, HfR, HfI, out_f);
        else      einsum_kernel<false><<<dim3(32, N / 32), 256, 0, stream>>>(W, tau, HfR, HfI, out_f);
    } else if (!cplx) {
        float* HfR = out_f + (size_t)(N - 64) * M;     // stash in last 64 real rows
        float* HfI = HfR + planeN;
        dft_fused<<<dim3(4, 32), 256, 0, stream>>>(H, HfR, HfI);
        einsum_kernel<false><<<dim3(32, (N - 64) / 32), 256, 0, stream>>>(W, tau, HfR, HfI, out_f);
        tail_real<<<dim3(128), 256, 0, stream>>>(W, tau, HfR, HfI, out_f);
    } else {
        float* HfR = out_f + 2 * (size_t)N * M - 2 * planeN;  // last 32 cplx rows
        float* HfI = HfR + planeN;
        dft_fused<<<dim3(4, 32), 256, 0, stream>>>(H, HfR, HfI);
        einsum_kernel<true ><<<dim3(32, (N - 32) / 32), 256, 0, stream>>>(W, tau, HfR, HfI, out_f);
        tail_cplx<<<dim3(16), 256, 0, stream>>>(W, tau, HfR, HfI, out_f);
    }
}

// Round 11
// 104.801 us; speedup vs baseline: 1.1733x; 1.0498x over previous
//
#include <hip/hip_runtime.h>
#include <math.h>

#ifndef M_PI
#define M_PI 3.14159265358979323846
#endif

constexpr int N    = 1024;
constexpr int M    = 4096;
constexpr int RANK = 32;
constexpr float PHI1 = -1.5339807878856412e-3f;   // -2*pi/4096

__device__ __forceinline__ float softplus_f(float x) {
    return (x > 0.0f) ? (x + log1pf(__expf(-x))) : log1pf(__expf(x));
}

// ===========================================================================
// DFT stage 1: G[d][r][k0] = sum_k1 sp(h[d][64k1+k0]) e^{-2pi i k1 r/64}
// grid (8 rG, 32 d), block 256.  ~1-2 us (validated R10).
// ===========================================================================
__global__ __launch_bounds__(256) void dft_s1(const float* __restrict__ H,
                                              float* __restrict__ GR,
                                              float* __restrict__ GI) {
    __shared__ float sh[M];              // 16 KB
    const int d = blockIdx.y, tid = threadIdx.x;
    const float4* H4 = (const float4*)(H + d * M);
    for (int i = tid; i < M / 4; i += 256) {
        const float4 v = H4[i];
        ((float4*)sh)[i] = make_float4(softplus_f(v.x), softplus_f(v.y),
                                       softplus_f(v.z), softplus_f(v.w));
    }
    __syncthreads();

    const int k0 = tid & 63;
    const int r0 = blockIdx.x * 8 + (tid >> 6) * 2;   // this thread: r0, r0+1
    float twR0 = 1.f, twI0 = 0.f, aR0 = 0.f, aI0 = 0.f;
    float twR1 = 1.f, twI1 = 0.f, aR1 = 0.f, aI1 = 0.f;
    float s0, c0, s1, c1;
    __sincosf((-2.0f * (float)M_PI / 64.0f) * (float)r0,       &s0, &c0);
    __sincosf((-2.0f * (float)M_PI / 64.0f) * (float)(r0 + 1), &s1, &c1);

    for (int k1 = 0; k1 < 64; ++k1) {
        const float h = sh[(k1 << 6) + k0];
        aR0 = fmaf(h, twR0, aR0);  aI0 = fmaf(h, twI0, aI0);
        aR1 = fmaf(h, twR1, aR1);  aI1 = fmaf(h, twI1, aI1);
        float nR = fmaf(twR0, c0, -twI0 * s0);
        float nI = fmaf(twR0, s0,  twI0 * c0);
        twR0 = nR; twI0 = nI;
        nR = fmaf(twR1, c1, -twI1 * s1);
        nI = fmaf(twR1, s1,  twI1 * c1);
        twR1 = nR; twI1 = nI;
    }
    const int base = d * 4096 + r0 * 64 + k0;
    GR[base]      = aR0;  GI[base]      = aI0;
    GR[base + 64] = aR1;  GI[base + 64] = aI1;
}

// ===========================================================================
// DFT stage 2: Hf[d][m] = sum_k0 G[d][m&63][k0] e^{-2pi i k0 m/4096}
// grid (16 mG, 32 d), block 256.  ~2 us (validated R10).
// ===========================================================================
__global__ __launch_bounds__(256) void dft_s2(const float* __restrict__ GR,
                                              const float* __restrict__ GI,
                                              float* __restrict__ HfR,
                                              float* __restrict__ HfI) {
    __shared__ float sGR[64 * 65], sGI[64 * 65];   // 33.3 KB
    const int d = blockIdx.y, tid = threadIdx.x;
    const float4* gr4 = (const float4*)(GR + d * 4096);
    const float4* gi4 = (const float4*)(GI + d * 4096);
    for (int i4 = tid; i4 < 1024; i4 += 256) {
        const int r = i4 >> 4, k0 = (i4 & 15) << 2;   // element = r*64 + k0
        const float4 vr = gr4[i4];
        const float4 vi = gi4[i4];
        const int p = r * 65 + k0;
        sGR[p] = vr.x; sGR[p+1] = vr.y; sGR[p+2] = vr.z; sGR[p+3] = vr.w;
        sGI[p] = vi.x; sGI[p+1] = vi.y; sGI[p+2] = vi.z; sGI[p+3] = vi.w;
    }
    __syncthreads();

    const int m = blockIdx.x * 256 + tid;
    const int rb = (m & 63) * 65;
    float ss, sc; __sincosf(PHI1 * (float)m, &ss, &sc);   // e^{-2pi i m/4096}
    float tR_ = 1.f, tI_ = 0.f, accR = 0.f, accI = 0.f;
    #pragma unroll 8
    for (int k0 = 0; k0 < 64; ++k0) {
        const float gr = sGR[rb + k0], gi = sGI[rb + k0];
        accR = fmaf(tR_, gr, fmaf(-tI_, gi, accR));
        accI = fmaf(tR_, gi, fmaf( tI_, gr, accI));
        const float nR = fmaf(tR_, sc, -tI_ * ss);
        const float nI = fmaf(tR_, ss,  tI_ * sc);
        tR_ = nR; tI_ = nI;
    }
    HfR[d * M + m] = accR;
    HfI[d * M + m] = accI;
}

// ===========================================================================
// dft_fused (no-ws fallback only — validated R5-R9).
// ===========================================================================
__global__ __launch_bounds__(256) void dft_fused(const float* __restrict__ H,
                                                 float* __restrict__ HfR,
                                                 float* __restrict__ HfI) {
    __shared__ float  sh[M];
    __shared__ float2 sG[64 * 65];
    const int d = blockIdx.y, tid = threadIdx.x;
    for (int k = tid; k < M; k += 256) sh[k] = softplus_f(H[d * M + k]);
    __syncthreads();

    const int k0 = tid & 63;
    const int rB = (tid >> 6) * 16;
    float twR[16], twI[16], stR[16], stI[16], aR[16], aI[16];
    #pragma unroll
    for (int rr = 0; rr < 16; ++rr) {
        const float ang = (-2.0f * (float)M_PI / 64.0f) * (float)(rB + rr);
        __sincosf(ang, &stI[rr], &stR[rr]);
        twR[rr] = 1.f; twI[rr] = 0.f; aR[rr] = 0.f; aI[rr] = 0.f;
    }
    for (int k1 = 0; k1 < 64; ++k1) {
        const float h = sh[(k1 << 6) + k0];
        #pragma unroll
        for (int rr = 0; rr < 16; ++rr) {
            aR[rr] = fmaf(h, twR[rr], aR[rr]);
            aI[rr] = fmaf(h, twI[rr], aI[rr]);
            const float nR = fmaf(twR[rr], stR[rr], -twI[rr] * stI[rr]);
            const float nI = fmaf(twR[rr], stI[rr],  twI[rr] * stR[rr]);
            twR[rr] = nR; twI[rr] = nI;
        }
    }
    #pragma unroll
    for (int rr = 0; rr < 16; ++rr)
        sG[k0 * 65 + rB + rr] = make_float2(aR[rr], aI[rr]);
    __syncthreads();

    const int mBase = blockIdx.x * 1024;
    for (int j = 0; j < 4; ++j) {
        const int m = mBase + j * 256 + tid;
        const int r = m & 63;
        float ss, sc; __sincosf(PHI1 * (float)m, &ss, &sc);
        float tR_ = 1.f, tI_ = 0.f, accR = 0.f, accI = 0.f;
        #pragma unroll 8
        for (int q = 0; q < 64; ++q) {
            const float2 g = sG[q * 65 + r];
            accR = fmaf(tR_, g.x, fmaf(-tI_, g.y, accR));
            accI = fmaf(tR_, g.y, fmaf( tI_, g.x, accI));
            const float nR = fmaf(tR_, sc, -tI_ * ss);
            const float nI = fmaf(tR_, ss,  tI_ * sc);
            tR_ = nR; tI_ = nI;
        }
        HfR[d * M + m] = accR;
        HfI[d * M + m] = accI;
    }
}

// ===========================================================================
// Einsum v6: same tiling/staging as v5b (validated), but the phasor advance
// uses the Chebyshev 3-term recurrence:  x_{j+1} = K*x_j - x_{j-1}, K=2cos(psi)
// (holds for both w*cos(th0+j*psi) and w*sin(th0+j*psi)).
// Inner cost per (n,d,m): real-out 2 acc + 2 recur = 4 fma (was 6).
// ===========================================================================
template <bool CPLX>
__global__ __launch_bounds__(256) void einsum_kernel(const float* __restrict__ W,
                                                     const float* __restrict__ tau,
                                                     const float* __restrict__ HfR,
                                                     const float* __restrict__ HfI,
                                                     float* __restrict__ out_f) {
    constexpr int U     = 2;
    constexpr int ROWS  = 32;
    constexpr int MT    = 128;
    __shared__ float2 sHf[16 * MT];
    __shared__ float  sW[ROWS][RANK], sT[ROWS][RANK];
    const int tid   = threadIdx.x;
    const int mBase = blockIdx.x * MT;
    const int nBase = blockIdx.y * ROWS;

    for (int i = tid; i < ROWS * RANK; i += 256) {
        const int n_ = i >> 5, dd = i & 31;
        sW[n_][dd] = softplus_f(W[(nBase + n_) * RANK + dd]);
        sT[n_][dd] = tau[(nBase + n_) * RANK + dd];
    }

    const int nl = tid >> 4, chunk = tid & 15;
    const int m0 = mBase + chunk;

    float accR[U][8], accI[U][8];
    #pragma unroll
    for (int u = 0; u < U; ++u)
        #pragma unroll
        for (int j = 0; j < 8; ++j) { accR[u][j] = 0.f; if (CPLX) accI[u][j] = 0.f; }

    for (int half = 0; half < 2; ++half) {
        __syncthreads();
        for (int e4 = tid; e4 < 16 * (MT / 2); e4 += 256) {   // 1024 float4, 4 iters
            const int dl = e4 >> 6, p = e4 & 63;              // 64 float4 per d-row
            const int base = (half * 16 + dl) * M + mBase + (p << 1);
            const float2 r2 = *(const float2*)(HfR + base);
            const float2 q2 = *(const float2*)(HfI + base);
            ((float4*)sHf)[e4] = make_float4(r2.x, q2.x, r2.y, q2.y);
        }
        __syncthreads();

        #pragma unroll 1
        for (int dl = 0; dl < 16; ++dl) {
            const int dd = (half << 4) + dl;
            // phasor state: (aR_,aI_) = phasor_j, (bR_,bI_) = phasor_{j+1}
            float aR_[U], aI_[U], bR_[U], bI_[U], K[U];
            #pragma unroll
            for (int u = 0; u < U; ++u) {
                const float t = sT[nl * U + u][dd], w = sW[nl * U + u][dd];
                const float a1 = PHI1 * t;
                float sp, cp; __sincosf(a1 * 16.0f, &sp, &cp);    // psi
                float s0, c0; __sincosf(a1 * (float)m0, &s0, &c0); // theta0
                aR_[u] = w * c0;                       // j=0
                aI_[u] = w * s0;
                bR_[u] = fmaf(aR_[u], cp, -aI_[u] * sp);   // j=1 (angle add)
                bI_[u] = fmaf(aI_[u], cp,  aR_[u] * sp);
                K[u]   = 2.0f * cp;
            }
            int idx = (dl << 7) + chunk;
            #pragma unroll
            for (int j = 0; j < 8; ++j) {
                const float2 h = sHf[idx];
                #pragma unroll
                for (int u = 0; u < U; ++u) {
                    accR[u][j] = fmaf(aR_[u], h.x, fmaf(-aI_[u], h.y, accR[u][j]));
                    if (CPLX) accI[u][j] = fmaf(aR_[u], h.y, fmaf(aI_[u], h.x, accI[u][j]));
                    const float nR = fmaf(K[u], bR_[u], -aR_[u]);  // Chebyshev
                    const float nI = fmaf(K[u], bI_[u], -aI_[u]);
                    aR_[u] = bR_[u]; aI_[u] = bI_[u];
                    bR_[u] = nR;     bI_[u] = nI;
                }
                idx += 16;
            }
        }
    }

    #pragma unroll
    for (int u = 0; u < U; ++u) {
        const int n = nBase + nl * U + u;
        if (CPLX) {
            float2* o2 = (float2*)out_f;
            #pragma unroll
            for (int j = 0; j < 8; ++j)
                o2[(size_t)n * M + m0 + (j << 4)] = make_float2(accR[u][j], accI[u][j]);
        } else {
            #pragma unroll
            for (int j = 0; j < 8; ++j)
                out_f[(size_t)n * M + m0 + (j << 4)] = accR[u][j];
        }
    }
}

// ===========================================================================
// Tail kernels (no-ws fallback only — dead given 268 MB ws).
// ===========================================================================
__global__ __launch_bounds__(256) void tail_real(const float* __restrict__ W,
                                                 const float* __restrict__ tau,
                                                 const float* __restrict__ stashR,
                                                 const float* __restrict__ stashI,
                                                 float* __restrict__ out_f) {
    __shared__ float stR[32 * 32], stI[32 * 32];
    __shared__ float sW[64][RANK], sT[64][RANK];
    const int tid = threadIdx.x;
    const int c0  = blockIdx.x * 32;
    const int nBase = N - 64;
    for (int i = tid; i < 64 * RANK; i += 256) {
        const int n_ = i >> 5, dd = i & 31;
        sW[n_][dd] = softplus_f(W[(nBase + n_) * RANK + dd]);
        sT[n_][dd] = tau[(nBase + n_) * RANK + dd];
    }
    for (int i = tid; i < 32 * 32; i += 256) {
        const int d_ = i >> 5, mm = i & 31;
        stR[i] = stashR[d_ * M + c0 + mm];
        stI[i] = stashI[d_ * M + c0 + mm];
    }
    __syncthreads();
    const int n = tid >> 2, chunk = tid & 3;
    const int m0 = c0 + chunk;
    float acc[8];
    #pragma unroll
    for (int j = 0; j < 8; ++j) acc[j] = 0.f;
    for (int d = 0; d < RANK; ++d) {
        const float t = sT[n][d], w = sW[n][d];
        const float a1 = PHI1 * t;
        float ss, sc; __sincosf(a1 * 4.0f, &ss, &sc);
        float s0, c0f; __sincosf(a1 * (float)m0, &s0, &c0f);
        float tR_ = w * c0f, tI_ = w * s0;
        int idx = (d << 5) + chunk;
        #pragma unroll
        for (int j = 0; j < 8; ++j) {
            acc[j] = fmaf(tR_, stR[idx], fmaf(-tI_, stI[idx], acc[j]));
            const float nR = fmaf(tR_, sc, -tI_ * ss);
            const float nI = fmaf(tR_, ss,  tI_ * sc);
            tR_ = nR; tI_ = nI;
            idx += 4;
        }
    }
    #pragma unroll
    for (int j = 0; j < 8; ++j)
        out_f[(size_t)(nBase + n) * M + m0 + (j << 2)] = acc[j];
}

__global__ __launch_bounds__(256) void tail_cplx(const float* __restrict__ W,
                                                 const float* __restrict__ tau,
                                                 const float* __restrict__ stashR,
                                                 const float* __restrict__ stashI,
                                                 float* __restrict__ out_f) {
    const int nBase = N - 32;
    __shared__ float sW[32][RANK], sT[32][RANK];
    const int tid = threadIdx.x, mBase = blockIdx.x * 256;
    for (int i = tid; i < 32 * RANK; i += 256) {
        const int n_ = i >> 5, dd = i & 31;
        sW[n_][dd] = softplus_f(W[(nBase + n_) * RANK + dd]);
        sT[n_][dd] = tau[(nBase + n_) * RANK + dd];
    }
    const int m = mBase + tid;
    float hr[RANK], hi[RANK];
    #pragma unroll
    for (int d = 0; d < RANK; ++d) { hr[d] = stashR[d * M + m]; hi[d] = stashI[d * M + m]; }
    __syncthreads();
    const float phi = PHI1 * (float)m;
    for (int n_ = 0; n_ < 32; ++n_) {
        float aR = 0.f, aI = 0.f;
        #pragma unroll
        for (int d = 0; d < RANK; ++d) {
            const float t = sT[n_][d], w = sW[n_][d];
            float s, c; __sincosf(t * phi, &s, &c);
            const float cw = c * w, sw = s * w;
            aR = fmaf(cw, hr[d], fmaf(-sw, hi[d], aR));
            aI = fmaf(cw, hi[d], fmaf( sw, hr[d], aI));
        }
        ((float2*)out_f)[(size_t)(nBase + n_) * M + m] = make_float2(aR, aI);
    }
}

// ---------------------------------------------------------------------------
extern "C" void kernel_launch(void* const* d_in, const int* in_sizes, int n_in,
                              void* d_out, int out_size, void* d_ws, size_t ws_size,
                              hipStream_t stream) {
    const float* W   = (const float*)d_in[0];
    const float* H   = (const float*)d_in[1];
    const float* tau = (const float*)d_in[2];
    float* out_f = (float*)d_out;

    const bool   cplx   = (out_size >= 2 * N * M);
    const size_t planeN = (size_t)RANK * M;            // 131072 floats / plane

    if (d_ws != nullptr && ws_size >= 4 * planeN * sizeof(float)) {
        float* HfR = (float*)d_ws;
        float* HfI = HfR + planeN;
        float* GR  = HfI + planeN;
        float* GI  = GR  + planeN;
        dft_s1<<<dim3(8, 32), 256, 0, stream>>>(H, GR, GI);
        dft_s2<<<dim3(16, 32), 256, 0, stream>>>(GR, GI, HfR, HfI);
        if (cplx) einsum_kernel<true ><<<dim3(32, N / 32), 256, 0, stream>>>(W, tau, HfR, HfI, out_f);
        else      einsum_kernel<false><<<dim3(32, N / 32), 256, 0, stream>>>(W, tau, HfR, HfI, out_f);
    } else if (!cplx) {
        float* HfR = out_f + (size_t)(N - 64) * M;     // stash in last 64 real rows
        float* HfI = HfR + planeN;
        dft_fused<<<dim3(4, 32), 256, 0, stream>>>(H, HfR, HfI);
        einsum_kernel<false><<<dim3(32, (N - 64) / 32), 256, 0, stream>>>(W, tau, HfR, HfI, out_f);
        tail_real<<<dim3(128), 256, 0, stream>>>(W, tau, HfR, HfI, out_f);
    } else {
        float* HfR = out_f + 2 * (size_t)N * M - 2 * planeN;  // last 32 cplx rows
        float* HfI = HfR + planeN;
        dft_fused<<<dim3(4, 32), 256, 0, stream>>>(H, HfR, HfI);
        einsum_kernel<true ><<<dim3(32, (N - 32) / 32), 256, 0, stream>>>(W, tau, HfR, HfI, out_f);
        tail_cplx<<<dim3(16), 256, 0, stream>>>(W, tau, HfR, HfI, out_f);
    }
}